// Round 5
// baseline (97.501 us; speedup 1.0000x reference)
//
#include <hip/hip_runtime.h>

#define N 1024
#define D 256

// ---------------- prep ----------------
// Two layouts written:
//  msT2[(g*N+row)*2+b] (j-side stream): b=0 -> (mu_{2g},mu_{2g+1})*rden,
//    b=1 -> (sig_{2g},sig_{2g+1}); pair j-read = (mu0,mu1,sig0,sig1) float4.
//  msI[pair*256 + g*2 + k] (i-side stream): same float4 content for row
//    2*pair+k, packed CONTIGUOUS per pair (4KB) so the pair kernel's
//    per-gg i-reads are one 64B-aligned s_load_dwordx16 group walking
//    sequential K$ lines (R1-R4 showed the 16KB-strided i-s_loads were
//    the stall: ~85% per-wave stall, prefetching j had no effect).
#define RI 8
#define LDW 260  // padded LDS row stride: %4==0 (float4 stores ok), +4 banks/row

__global__ __launch_bounds__(256) void prep3(
    const float* __restrict__ muX, const float* __restrict__ ls,
    float2* __restrict__ msT2, float4* __restrict__ msI4) {
  const int i0 = blockIdx.x * RI;
  const int t = threadIdx.x;
  __shared__ float smu[RI][LDW];
  __shared__ float ssg[RI][LDW];
  __shared__ float sred[RI][32];
  __shared__ float rden[RI];
  const float4* mu4 = (const float4*)(muX + (size_t)i0 * D);
  const float4* ls4 = (const float4*)(ls + (size_t)i0 * D);
#pragma unroll
  for (int u = 0; u < 2; ++u) {
    const int idx = u * 256 + t;  // float4 index within the 8x256 row block
    const int row = idx >> 6, c4 = idx & 63;
    const float4 v = mu4[idx];
    *(float4*)&smu[row][c4 * 4] = v;
    const float4 e = ls4[idx];
    float4 x;
    x.x = __expf(e.x) + 5e-11f; x.y = __expf(e.y) + 5e-11f;  // eps folded
    x.z = __expf(e.z) + 5e-11f; x.w = __expf(e.w) + 5e-11f;
    *(float4*)&ssg[row][c4 * 4] = x;
  }
  __syncthreads();
  {
    const int r = t >> 5, q = t & 31;  // 32 lanes per row
    float s = 0.f;
#pragma unroll
    for (int k = 0; k < 8; ++k) {
      const float v = smu[r][q + 32 * k];
      s = fmaf(v, v, s);
    }
    sred[r][q] = s;
  }
  __syncthreads();
  if (t < RI) {
    float tot = 0.f;
    for (int u = 0; u < 32; ++u) tot += sred[t][u];
    rden[t] = 1.0f / fmaxf(sqrtf(tot), 1e-12f);  // F.normalize eps
  }
  __syncthreads();
  // j-side layout
#pragma unroll
  for (int pass = 0; pass < 8; ++pass) {
    const int f = pass * 256 + t;
    const int b = f & 1, il = (f >> 1) & 7, g = f >> 4;
    const float* src = b ? &ssg[il][0] : &smu[il][0];
    const float sc = b ? 1.0f : rden[il];
    msT2[((size_t)g * N + i0 + il) * 2 + b] =
        make_float2(src[2 * g] * sc, src[2 * g + 1] * sc);
  }
  // i-side contiguous layout: 4 pairs x 256 float4 per block, coalesced
#pragma unroll
  for (int pass = 0; pass < 4; ++pass) {
    const int f = pass * 256 + t;
    const int pr = f >> 8, rem = f & 255, g = rem >> 1, k = rem & 1;
    const int il = pr * 2 + k;
    const float r = rden[il];
    msI4[((size_t)(blockIdx.x * 4 + pr)) * 256 + rem] =
        make_float4(smu[il][2 * g] * r, smu[il][2 * g + 1] * r,
                    ssg[il][2 * g], ssg[il][2 * g + 1]);
  }
}

// ---------------- pair ----------------
// Triangular 2x128 tiles: 2304 blocks x 2 waves = 4608 waves = 4.5/SIMD.
// i-side: contiguous per-pair 4KB slab (msI), wave-uniform 64B groups ->
// sequential s_load stream. j-side: distance-2 register prefetch.
// Combined-denominator: one rcp per 4 d's; p *= den reused for ln-sum.
__global__ __launch_bounds__(128) void pair_kernel(
    const float4* __restrict__ msT4, const float4* __restrict__ msI4,
    float* __restrict__ out) {
  int L = blockIdx.x;
  int js = 0, base = 0;  // slab js has 64*(js+1) row-tiles of 2 rows
  while (L >= base + 64 * (js + 1)) { base += 64 * (js + 1); ++js; }
  const int ib = L - base;
  const int j0 = js * 128, i0 = ib * 2;
  const bool diag = (ib >= js * 64);  // tile straddles the diagonal
  const int j = j0 + threadIdx.x;

  float acc[2] = {0.f, 0.f};
  float p[2] = {1.f, 1.f};
  int ea[2] = {0, 0};

  const float4* Jp = msT4 + j;                      // lane-varying base
  const float4* Ip = msI4 + (size_t)ib * 256;       // wave-uniform 4KB slab

#define PAIR_COMPUTE(G, JA, JB)                                         \
  do {                                                                  \
    _Pragma("unroll") for (int k = 0; k < 2; ++k) {                     \
      const float4 iva = Ip[4 * (G) + k];      /* row 2G,   uniform */  \
      const float4 ivb = Ip[4 * (G) + 2 + k];  /* row 2G+1, uniform */  \
      const float sa0 = iva.z + (JA).z, sa1 = iva.w + (JA).w;           \
      const float da0 = iva.x - (JA).x, da1 = iva.y - (JA).y;           \
      const float sb0 = ivb.z + (JB).z, sb1 = ivb.w + (JB).w;           \
      const float db0 = ivb.x - (JB).x, db1 = ivb.y - (JB).y;           \
      const float qa0 = da0 * da0, qa1 = da1 * da1;                     \
      const float qb0 = db0 * db0, qb1 = db1 * db1;                     \
      const float s01 = sa0 * sa1, s23 = sb0 * sb1;                     \
      float na = qa0 * sa1; na = fmaf(qa1, sa0, na);                    \
      float nb = qb0 * sb1; nb = fmaf(qb1, sb0, nb);                    \
      float num = na * s23; num = fmaf(nb, s01, num);                   \
      const float den = s01 * s23;                                      \
      acc[k] = fmaf(num, __builtin_amdgcn_rcpf(den), acc[k]);           \
      p[k] *= den;                                                      \
    }                                                                   \
  } while (0)

  // prologue: j rows 0..3 (iterations gg=0,1)
  float4 A0 = Jp[(size_t)0 * N], B0 = Jp[(size_t)1 * N];
  float4 A1 = Jp[(size_t)2 * N], B1 = Jp[(size_t)3 * N];

#pragma unroll 2
  for (int gg = 0; gg < D / 4; gg += 2) {  // two 4-d iterations per body
    // prefetch j rows for gg+2 / gg+3 (clamped, wave-uniform SALU select)
    const int r4 = (2 * gg + 4 < D / 2) ? 2 * gg + 4 : 0;
    const int r6 = (2 * gg + 6 < D / 2) ? 2 * gg + 6 : 0;
    float4 A2 = Jp[(size_t)r4 * N];
    float4 B2 = Jp[(size_t)(r4 + 1) * N];
    PAIR_COMPUTE(gg, A0, B0);
    float4 A3 = Jp[(size_t)r6 * N];
    float4 B3 = Jp[(size_t)(r6 + 1) * N];
    PAIR_COMPUTE(gg + 1, A1, B1);
    A0 = A2; B0 = B2; A1 = A3; B1 = B3;
    {  // strip every 8 d's: |log2 p| bounded -> exponent safe
#pragma unroll
      for (int k = 0; k < 2; ++k) {
        const int bb = __float_as_int(p[k]);
        ea[k] += bb >> 23;
        p[k] = __int_as_float((bb & 0x007fffff) | 0x3f800000);
      }
    }
  }
#undef PAIR_COMPUTE

  constexpr float LN2 = 0.6931471805599453f;
  float v[2];
#pragma unroll
  for (int k = 0; k < 2; ++k) {
    const float lg2 = (float)(ea[k] - 127 * (D / 8)) + __log2f(p[k]);
    v[k] = -(acc[k] + LN2 * lg2);
  }

  if (!diag) {  // strictly-upper tile: unmasked direct + mirror writes
    out[(size_t)i0 * N + j] = v[0];
    out[(size_t)(i0 + 1) * N + j] = v[1];
    *(float2*)(out + (size_t)j * N + i0) = make_float2(v[0], v[1]);
  } else {  // diagonal tile: per-element masks
#pragma unroll
    for (int k = 0; k < 2; ++k) {
      const int i = i0 + k;
      if (j >= i) out[(size_t)i * N + j] = v[k];
      if (j > i) out[(size_t)j * N + i] = v[k];
    }
  }
}

extern "C" void kernel_launch(void* const* d_in, const int* in_sizes, int n_in,
                              void* d_out, int out_size, void* d_ws, size_t ws_size,
                              hipStream_t stream) {
  const float* muX = (const float*)d_in[0];
  const float* ls  = (const float*)d_in[1];
  float* out = (float*)d_out;
  float2* msT2 = (float2*)d_ws;                          // 2 MB j-side layout
  float4* msI4 = (float4*)((char*)d_ws + (size_t)2 * N * D * sizeof(float));
  // msI: N/2 pairs x 256 float4 = 2 MB i-side layout (ws needs >= 4 MB)
  prep3<<<dim3(N / RI), dim3(256), 0, stream>>>(muX, ls, msT2, msI4);
  const int nblocks = 64 * (8 * 9 / 2);  // 2304 triangular 2x128 tiles
  pair_kernel<<<dim3(nblocks), dim3(128), 0, stream>>>((const float4*)msT2,
                                                       (const float4*)msI4,
                                                       out);
}